// Round 1
// 199.815 us; speedup vs baseline: 1.0034x; 1.0034x over previous
//
#include <hip/hip_runtime.h>
#include <hip/hip_bf16.h>

// Problem constants: G=64, C=32, L=128, D=64, H=128, NCLS=10
#define NSEQ 2048   // G*C
#define LSEQ 128
#define DIN  64
#define HID  128
#define NCLS 10

typedef __attribute__((ext_vector_type(8))) short bfrag8;   // 8 bf16 (MFMA A/B frag)
typedef __attribute__((ext_vector_type(4))) float facc4;    // MFMA C/D frag

__device__ __forceinline__ short f2bf(float f) {
    union { __hip_bfloat16 b; short s; } u;
    u.b = __float2bfloat16(f);   // RNE
    return u.s;
}

__device__ __forceinline__ bfrag8 load_bf16_frag(const float* __restrict__ p) {
    bfrag8 r;
#pragma unroll
    for (int j = 0; j < 8; ++j) r[j] = f2bf(p[j]);
    return r;
}

__device__ __forceinline__ float fast_sigmoid(float x) {
    float e = __builtin_amdgcn_exp2f(-1.4426950408889634f * x);
    return __builtin_amdgcn_rcpf(1.0f + e);
}
__device__ __forceinline__ float fast_tanh(float x) {
    float e = __builtin_amdgcn_exp2f(2.8853900817779268f * x);
    return 1.0f - 2.0f * __builtin_amdgcn_rcpf(1.0f + e);
}

// v_permlane32_swap_b32 d, s — HW-verified d-output semantics:
//   d_new.lo = d_old.lo ; d_new.hi[i+32] = s_old[i]
// seq map qd0:{0,1} qd1:{4,5} qd2:{2,3} qd3:{6,7}.
__device__ __forceinline__ float lane_redistribute(float r_low, float r_high) {
    float d = r_low, s = r_high;
    asm("v_permlane32_swap_b32 %0, %1" : "+v"(d), "+v"(s));
    return d;
}

// Wave-specialized LSTM: one block = 8 sequences, 16 waves.
//   waves 0-7  (consumers): h-recurrence MFMAs + LSTM cell only.
//   waves 8-15 (producers): xg(t) = bias + x(t)@Wih^T, 2 steps ahead, into a
//                           3-deep f32 LDS ring (identical numerics to before).
// x flows producer-side through a tiny 2-deep bf16 stage (coalesced row loads,
// pipelined 1 step ahead). One barrier per step; role loops have matched
// barrier counts (1 prologue + 128 loop).
__global__ __launch_bounds__(1024) void lstm_fused(
    const float* __restrict__ x,      // [2048][128][64] f32
    const float* __restrict__ Wih,    // [512][64] f32
    const float* __restrict__ Whh,    // [512][128] f32
    const float* __restrict__ bih,    // [512] f32
    const float* __restrict__ bhh,    // [512] f32
    float* __restrict__ rep)          // [2048][128] f32 (d_ws)
{
    __shared__ __align__(16) __hip_bfloat16 hbuf[2][8][136];   // 4352 B (rows 8-15 of M dup'd, outputs discarded)
    __shared__ __align__(16) float xgbuf[3][512][8];           // 49152 B ring: [buf][gatecol][seqrow]
    __shared__ __align__(16) __hip_bfloat16 xstage[2][8][72];  // 2304 B: x(t) rows, bf16

    const int tid  = threadIdx.x;
    const int w    = tid >> 6;
    const int lane = tid & 63;
    const int ln   = lane & 15;
    const int qd   = lane >> 4;
    const int s0   = blockIdx.x * 8;

    if (w < 8) {
        // ================= consumer: recurrence + cell =================
        const int khid = w * 16 + ln;
        const int sq0  = (qd & 1) * 4 + (qd >> 1) * 2;   // {0,4,2,6}
        const int sq1  = sq0 + 1;

        bfrag8 whr[4][4];
#pragma unroll
        for (int g = 0; g < 4; ++g) {
            const int col = g * HID + khid;
#pragma unroll
            for (int k0 = 0; k0 < 4; ++k0)
                whr[g][k0] = load_bf16_frag(Whh + col * HID + k0 * 32 + qd * 8);
        }

        // zero both h buffers (h(-1) = 0); consumers are tids 0..511
        {
            unsigned int* ph = (unsigned int*)&hbuf[0][0][0];
            for (int i = tid; i < 2 * 8 * 136 / 2; i += 512) ph[i] = 0u;
        }

        float cst[2]  = {0.f, 0.f};
        float hsum[2] = {0.f, 0.f};

        __syncthreads();                                   // B0 (xg(0),xg(1) ready)

        const int xoff = khid * 8 + (qd & 1) * 4;          // qd>=2 lanes: garbage rows, discarded
        facc4 acc[4];
#pragma unroll
        for (int g = 0; g < 4; ++g)
            acc[g] = *(const facc4*)(&xgbuf[0][0][0] + g * 1024 + xoff);

        int cur = 0, bufN = 1;
#pragma unroll 1
        for (int t = 0; t < LSEQ; ++t) {
            // h A-frags (rows dup'd via ln&7 -> output rows 8-15 garbage, discarded)
            bfrag8 hf0 = *(const bfrag8*)(&hbuf[cur][ln & 7][qd * 8]);
            bfrag8 hf1 = *(const bfrag8*)(&hbuf[cur][ln & 7][32 + qd * 8]);
            bfrag8 hf2 = *(const bfrag8*)(&hbuf[cur][ln & 7][64 + qd * 8]);
            bfrag8 hf3 = *(const bfrag8*)(&hbuf[cur][ln & 7][96 + qd * 8]);
            __builtin_amdgcn_s_setprio(1);
#pragma unroll
            for (int g = 0; g < 4; ++g) {
                acc[g] = __builtin_amdgcn_mfma_f32_16x16x32_bf16(hf0, whr[g][0], acc[g], 0, 0, 0);
                acc[g] = __builtin_amdgcn_mfma_f32_16x16x32_bf16(hf1, whr[g][1], acc[g], 0, 0, 0);
                acc[g] = __builtin_amdgcn_mfma_f32_16x16x32_bf16(hf2, whr[g][2], acc[g], 0, 0, 0);
                acc[g] = __builtin_amdgcn_mfma_f32_16x16x32_bf16(hf3, whr[g][3], acc[g], 0, 0, 0);
            }
            __builtin_amdgcn_s_setprio(0);

            float u0[4], u1[4];
#pragma unroll
            for (int g = 0; g < 4; ++g) {
                u0[g] = lane_redistribute(acc[g][0], acc[g][2]);
                u1[g] = lane_redistribute(acc[g][1], acc[g][3]);
            }

            // prefetch next step's C-input (bias + xg(t+1)); written at step t-1,
            // consumed after the next barrier -> latency fully hidden.
            {
                const float* xgN = &xgbuf[bufN][0][0] + xoff;
#pragma unroll
                for (int g = 0; g < 4; ++g)
                    acc[g] = *(const facc4*)(xgN + g * 1024);
            }

            short hb[2];
#pragma unroll
            for (int j = 0; j < 2; ++j) {
                float iv = fast_sigmoid(j ? u1[0] : u0[0]);
                float fv = fast_sigmoid(j ? u1[1] : u0[1]);
                float gv = fast_tanh   (j ? u1[2] : u0[2]);
                float ov = fast_sigmoid(j ? u1[3] : u0[3]);
                float c  = fv * cst[j] + iv * gv;
                cst[j]   = c;
                float hv = ov * fast_tanh(c);
                hsum[j] += hv;
                hb[j]    = f2bf(hv);
            }
            ((short*)&hbuf[cur ^ 1][sq0][0])[khid] = hb[0];
            ((short*)&hbuf[cur ^ 1][sq1][0])[khid] = hb[1];

            __syncthreads();                               // B1..B128
            cur ^= 1;
            bufN = (bufN == 2) ? 0 : bufN + 1;
        }

        rep[(size_t)(s0 + sq0) * HID + khid] = hsum[0];
        rep[(size_t)(s0 + sq1) * HID + khid] = hsum[1];
    } else {
        // ================= producer: xg(t) 2 steps ahead =================
        const int p = w - 8;
        const int colbase = p * 16 + ln;

        bfrag8 wir[4][2];
        facc4  biasf[4];
#pragma unroll
        for (int g = 0; g < 4; ++g) {
            const int col = g * HID + colbase;
            const float b = bih[col] + bhh[col];
            biasf[g] = (facc4){b, b, b, b};
#pragma unroll
            for (int k0 = 0; k0 < 2; ++k0)
                wir[g][k0] = load_bf16_frag(Wih + col * DIN + k0 * 32 + qd * 8);
        }

        // prologue: xg(0)->buf0, xg(1)->buf1 from direct (dup-row) global loads
        const float* xr = x + (size_t)(s0 + (ln & 7)) * (LSEQ * DIN) + qd * 8;
#pragma unroll
        for (int tt = 0; tt < 2; ++tt) {
            float4 a00 = *(const float4*)(xr + tt * DIN);
            float4 a01 = *(const float4*)(xr + tt * DIN + 4);
            float4 a10 = *(const float4*)(xr + tt * DIN + 32);
            float4 a11 = *(const float4*)(xr + tt * DIN + 36);
            bfrag8 xf0, xf1;
#pragma unroll
            for (int j = 0; j < 4; ++j) {
                xf0[j] = f2bf(((float*)&a00)[j]); xf0[4 + j] = f2bf(((float*)&a01)[j]);
                xf1[j] = f2bf(((float*)&a10)[j]); xf1[4 + j] = f2bf(((float*)&a11)[j]);
            }
#pragma unroll
            for (int g = 0; g < 4; ++g) {
                facc4 a = __builtin_amdgcn_mfma_f32_16x16x32_bf16(xf0, wir[g][0], biasf[g], 0, 0, 0);
                a = __builtin_amdgcn_mfma_f32_16x16x32_bf16(xf1, wir[g][1], a, 0, 0, 0);
                if (qd < 2)
                    *(facc4*)(&xgbuf[tt][0][0] + (g * 128 + colbase) * 8 + qd * 4) = a;
            }
        }

        // stage x(2) -> xstage[0] (one coalesced row per producer wave), issue x(3)
        const float* xsrow = x + (size_t)(s0 + p) * (LSEQ * DIN) + lane;
        xstage[0][p][lane] = __float2bfloat16(xsrow[2 * DIN]);
        float xnext = xsrow[3 * DIN];

        __syncthreads();                                   // B0

        int bufW = 2;
#pragma unroll 1
        for (int t = 0; t < LSEQ; ++t) {
            if (t < LSEQ - 2) {
                // A-frags of x(t+2) from stage written at step t-1
                bfrag8 xf0 = *(const bfrag8*)(&xstage[(t + 2) & 1][ln & 7][qd * 8]);
                bfrag8 xf1 = *(const bfrag8*)(&xstage[(t + 2) & 1][ln & 7][32 + qd * 8]);
                if (t < LSEQ - 3) {
                    xstage[(t + 3) & 1][p][lane] = __float2bfloat16(xnext);
                    if (t < LSEQ - 4) xnext = xsrow[(t + 4) * DIN];
                }
#pragma unroll
                for (int g = 0; g < 4; ++g) {
                    facc4 a = __builtin_amdgcn_mfma_f32_16x16x32_bf16(xf0, wir[g][0], biasf[g], 0, 0, 0);
                    a = __builtin_amdgcn_mfma_f32_16x16x32_bf16(xf1, wir[g][1], a, 0, 0, 0);
                    if (qd < 2)
                        *(facc4*)(&xgbuf[bufW][0][0] + (g * 128 + colbase) * 8 + qd * 4) = a;
                }
            }
            __syncthreads();                               // B1..B128
            bufW = (bufW == 2) ? 0 : bufW + 1;
        }
    }
}

// Epilogue: graph mean over C=32, classifier [10,128], log-softmax -> f32 out[64][10]
__global__ __launch_bounds__(128) void cls_kernel(
    const float* __restrict__ rep,    // [2048][128]
    const float* __restrict__ Wcls,   // [10][128]
    const float* __restrict__ bcls,   // [10]
    float* __restrict__ out)          // [64][10]
{
    __shared__ float m_s[HID];
    __shared__ float logits_s[NCLS];
    const int g = blockIdx.x;
    const int h = threadIdx.x;

    float s = 0.f;
#pragma unroll 4
    for (int c = 0; c < 32; ++c)
        s += rep[((size_t)g * 32 + c) * HID + h];
    m_s[h] = s * (1.0f / 32.0f);
    __syncthreads();

    if (h < NCLS) {
        float acc = bcls[h];
        for (int k = 0; k < HID; ++k)
            acc += m_s[k] * Wcls[h * HID + k];
        logits_s[h] = acc;
    }
    __syncthreads();

    if (h < NCLS) {
        float mx = logits_s[0];
#pragma unroll
        for (int j = 1; j < NCLS; ++j) mx = fmaxf(mx, logits_s[j]);
        float se = 0.f;
#pragma unroll
        for (int j = 0; j < NCLS; ++j)
            se += __builtin_amdgcn_exp2f((logits_s[j] - mx) * 1.4426950408889634f);
        float lse = mx + 0.6931471805599453f * __builtin_amdgcn_logf(se);
        out[g * NCLS + h] = logits_s[h] - lse;
    }
}

extern "C" void kernel_launch(void* const* d_in, const int* in_sizes, int n_in,
                              void* d_out, int out_size, void* d_ws, size_t ws_size,
                              hipStream_t stream) {
    const float* x    = (const float*)d_in[0];
    const float* Wih  = (const float*)d_in[1];
    const float* Whh  = (const float*)d_in[2];
    const float* bih  = (const float*)d_in[3];
    const float* bhh  = (const float*)d_in[4];
    const float* Wcls = (const float*)d_in[5];
    const float* bcls = (const float*)d_in[6];

    float* rep = (float*)d_ws;   // 2048*128 fp32 = 1 MB scratch

    lstm_fused<<<NSEQ / 8, 1024, 0, stream>>>(x, Wih, Whh, bih, bhh, rep);
    cls_kernel<<<64, 128, 0, stream>>>(rep, Wcls, bcls, (float*)d_out);
}